// Round 7
// baseline (4080.759 us; speedup 1.0000x reference)
//
#include <hip/hip_runtime.h>
#include <cstdint>

#define K_IN   4096
#define N_OUT  4096
#define M_ROWS 16384
#define RANK   8
#define LSCALE 1.0f   // alpha/rank = 8/8
#define NT     128    // K_IN / 32  (BK=32 K-tiles)

typedef __attribute__((ext_vector_type(8))) short  short8;
typedef __attribute__((ext_vector_type(4))) float  floatx4;

__device__ __forceinline__ unsigned short f2bf(float f) {
  uint32_t u = __float_as_uint(f);
  u += 0x7FFFu + ((u >> 16) & 1u);
  return (unsigned short)(u >> 16);
}

__global__ __launch_bounds__(256) void fold_w_kernel(
    const float* __restrict__ W, const float* __restrict__ lA,
    const float* __restrict__ lB, unsigned short* __restrict__ Weff) {
  int idx = blockIdx.x * 256 + threadIdx.x;
  int o = idx >> 10;
  int k = (idx & 1023) << 2;
  float4 w = *reinterpret_cast<const float4*>(W + (size_t)o * K_IN + k);
#pragma unroll
  for (int r = 0; r < RANK; ++r) {
    float s = LSCALE * lB[o * RANK + r];
    float4 a = *reinterpret_cast<const float4*>(lA + r * K_IN + k);
    w.x += s * a.x; w.y += s * a.y; w.z += s * a.z; w.w += s * a.w;
  }
  ushort4 p;
  p.x = f2bf(w.x); p.y = f2bf(w.y); p.z = f2bf(w.z); p.w = f2bf(w.w);
  *reinterpret_cast<ushort4*>(Weff + (size_t)o * K_IN + k) = p;
}

__global__ __launch_bounds__(256) void cvt_x_kernel(
    const float* __restrict__ x, unsigned short* __restrict__ xb) {
  size_t i = ((size_t)blockIdx.x * 256 + threadIdx.x) * 8;
  float4 a = *reinterpret_cast<const float4*>(x + i);
  float4 c = *reinterpret_cast<const float4*>(x + i + 4);
  uint4 v;
  v.x = (uint32_t)f2bf(a.x) | ((uint32_t)f2bf(a.y) << 16);
  v.y = (uint32_t)f2bf(a.z) | ((uint32_t)f2bf(a.w) << 16);
  v.z = (uint32_t)f2bf(c.x) | ((uint32_t)f2bf(c.y) << 16);
  v.w = (uint32_t)f2bf(c.z) | ((uint32_t)f2bf(c.w) << 16);
  *reinterpret_cast<uint4*>(xb + i) = v;
}

__device__ __forceinline__ void gload_lds16(const void* g, void* l) {
  __builtin_amdgcn_global_load_lds(
      (const __attribute__((address_space(1))) void*)g,
      (__attribute__((address_space(3))) void*)l, 16, 0, 0);
}

// ---------------------------------------------------------------------------
// 256x256 tile, BK=32, 512 threads (8 waves: 2M x 4N), 2 phases/K-tile,
// double-buffered LDS 2 x 32KB = 64KB -> 2 BLOCKS/CU (16 waves, 4/SIMD).
// ROUND-7 CHANGE (T4-via-TLP): R5/R6 at 1 block/CU had 2 waves/SIMD — every
// barrier/lgkm/vmcnt stall idled the SIMD (wall 5316 cyc/K-tile = MFMA 2483
// + LDS + overhead, additive; R6's ILP pipelining regressed to 5730).
// With 2 co-resident blocks the other block's waves fill every stall.
// Per buffer (32KB): A 256x32 bf16 (16KB, 64B rows) | B same.
// Swizzle (HW-validated R2-R6): L(r,s)=((r<<6)|(s<<4))^((r&7)<<4) within a
// 16KB matrix tile; global_load_lds dest linear, source pre-swizzled.
// Phase map per K-tile t:
//   P0: ds-read af(mh0) 4x + bf 4x | stage A,B(t+1) (4 gloads) | BAR |
//       lgkm0 | setprio 16xMFMA | BAR
//   P1: ds-read af(mh1) 4x | BAR | lgkm0 | setprio 16xMFMA |
//       vmcnt(0) if more | BAR
// vmcnt ledger: {A,B}(t+1) issued top of P0(t), certified end of P1(t)
// (~2 phases > HBM latency); the drain-to-0 is covered by the co-resident
// block (the deliberate A/B vs R6's counted-vmcnt ILP).
// WAR: STAGE(t+1) writes buf (t+1)&1, last read in tile t-1, drained by
// lgkm0 + >=2 barriers before the DMA issues.
// ---------------------------------------------------------------------------
__global__ __launch_bounds__(512, 4) void gemm_kernel(
    const unsigned short* __restrict__ Xb, const unsigned short* __restrict__ Wb,
    const float* __restrict__ bias, float* __restrict__ out) {
  __shared__ alignas(16) char lds[2 * 32768];   // 64 KiB -> 2 blocks/CU

  const int tid  = threadIdx.x;
  const int wave = tid >> 6, lane = tid & 63;
  const int wr = wave >> 2, wc = wave & 3;      // 2 (M) x 4 (N) wave grid
  const int l15 = lane & 15, sq = lane >> 4;
  const int xorv = (l15 & 7) << 4;

  // XCD swizzle: 1024 blocks (%8==0), contiguous 128-tile chunk per XCD
  int bx  = blockIdx.x;
  int sbx = (bx & 7) * 128 + (bx >> 3);
  const int mt = sbx >> 4;   // 0..63
  const int nt = sbx & 15;   // 0..15

  // staging source pre-swizzle: linear LDS byte L -> logical (r,s):
  //   r = (L>>7)*2 | ((L>>6 ^ L>>8)&1),  s = ((L>>4)&3) ^ (r&3)
  const unsigned short *gA0, *gA1, *gB0, *gB1;
  {
    int L0 = tid * 16;
    int r0 = ((L0 >> 7) << 1) | (((L0 >> 6) ^ (L0 >> 8)) & 1);
    int s0 = ((L0 >> 4) & 3) ^ (r0 & 3);
    gA0 = Xb + (size_t)(mt * 256 + r0) * K_IN + s0 * 8;
    gB0 = Wb + (size_t)(nt * 256 + r0) * K_IN + s0 * 8;
    int L1 = 8192 + tid * 16;
    int r1 = ((L1 >> 7) << 1) | (((L1 >> 6) ^ (L1 >> 8)) & 1);
    int s1 = ((L1 >> 4) & 3) ^ (r1 & 3);
    gA1 = Xb + (size_t)(mt * 256 + r1) * K_IN + s1 * 8;
    gB1 = Wb + (size_t)(nt * 256 + r1) * K_IN + s1 * 8;
  }

#define STAGE_AB(TT) do {                                            \
    char* d_ = lds + ((TT) & 1) * 32768 + tid * 16;                  \
    gload_lds16(gA0 + (TT) * 32, d_);                                \
    gload_lds16(gA1 + (TT) * 32, d_ + 8192);                         \
    gload_lds16(gB0 + (TT) * 32, d_ + 16384);                        \
    gload_lds16(gB1 + (TT) * 32, d_ + 24576);                        \
  } while (0)
#define BAR() do { asm volatile("" ::: "memory");                    \
    __builtin_amdgcn_s_barrier();                                    \
    asm volatile("" ::: "memory"); } while (0)
#define LGKM0() asm volatile("s_waitcnt lgkmcnt(0)" ::: "memory")
#define LOAD_AF(MH) do {                                             \
    const char* Ah_ = lds + tb;                                      \
    _Pragma("unroll")                                                \
    for (int i = 0; i < 4; ++i) {                                    \
      int rA_ = wr * 128 + ((MH) * 4 + i) * 16 + l15;                \
      int LA_ = ((rA_ << 6) | (sq << 4)) ^ xorv;                     \
      af[i] = *reinterpret_cast<const short8*>(Ah_ + LA_);           \
    } } while (0)
#define LOAD_BF() do {                                               \
    const char* Bh_ = lds + tb + 16384;                              \
    _Pragma("unroll")                                                \
    for (int j = 0; j < 4; ++j) {                                    \
      int rB_ = wc * 64 + j * 16 + l15;                              \
      int LB_ = ((rB_ << 6) | (sq << 4)) ^ xorv;                     \
      bf[j] = *reinterpret_cast<const short8*>(Bh_ + LB_);           \
    } } while (0)
#define DO_MFMA(MH) do {                                             \
    __builtin_amdgcn_s_setprio(1);                                   \
    _Pragma("unroll")                                                \
    for (int i = 0; i < 4; ++i)                                      \
      _Pragma("unroll")                                              \
      for (int j = 0; j < 4; ++j)                                    \
        acc[(MH) * 4 + i][j] = __builtin_amdgcn_mfma_f32_16x16x32_bf16( \
            af[i], bf[j], acc[(MH) * 4 + i][j], 0, 0, 0);            \
    __builtin_amdgcn_s_setprio(0); } while (0)

  floatx4 acc[8][4];
#pragma unroll
  for (int i = 0; i < 8; ++i)
#pragma unroll
    for (int j = 0; j < 4; ++j)
      acc[i][j] = (floatx4){0.f, 0.f, 0.f, 0.f};

  // prologue: stage tile 0, certify, release
  STAGE_AB(0);
  asm volatile("s_waitcnt vmcnt(0)" ::: "memory");
  BAR();

  short8 af[4], bf[4];

  for (int t = 0; t < NT; ++t) {
    const int tb = (t & 1) * 32768;
    const bool more = (t + 1 < NT);

    // ---- P0: read af(mh0)+bf; stage {A,B}(t+1); MFMA(mh0)
    LOAD_AF(0);
    LOAD_BF();
    if (more) STAGE_AB(t + 1);
    BAR(); LGKM0();
    DO_MFMA(0);
    BAR();

    // ---- P1: read af(mh1); MFMA(mh1); certify {A,B}(t+1)
    LOAD_AF(1);
    BAR(); LGKM0();
    DO_MFMA(1);
    if (more) asm volatile("s_waitcnt vmcnt(0)" ::: "memory");
    BAR();
  }
#undef STAGE_AB
#undef LOAD_AF
#undef LOAD_BF
#undef DO_MFMA

  // epilogue: C/D layout col=lane&15, row=(lane>>4)*4+reg (m89/m91 verified)
  const int row0 = mt * 256 + wr * 128 + sq * 4;
  const int col0 = nt * 256 + wc * 64 + l15;
#pragma unroll
  for (int j = 0; j < 4; ++j) {
    int col = col0 + j * 16;
    float bv = bias[col];
#pragma unroll
    for (int i = 0; i < 8; ++i) {
      int rowb = row0 + i * 16;
#pragma unroll
      for (int rr = 0; rr < 4; ++rr)
        out[(size_t)(rowb + rr) * N_OUT + col] = acc[i][j][rr] + bv;
    }
  }
}

// self-contained correct fallback (only if ws too small): tiled fp32
__global__ __launch_bounds__(256) void fallback_kernel(
    const float* __restrict__ x, const float* __restrict__ W,
    const float* __restrict__ bias, const float* __restrict__ lA,
    const float* __restrict__ lB, float* __restrict__ out) {
  __shared__ float Xs[64][17];
  __shared__ float Ws[64][17];
  int tid = threadIdx.x;
  int tx = tid & 15, ty = tid >> 4;
  int bm = blockIdx.y * 64, bn = blockIdx.x * 64;
  float acc[4][4] = {};
  for (int k0 = 0; k0 < K_IN; k0 += 16) {
#pragma unroll
    for (int q = 0; q < 4; ++q) {
      int flat = q * 256 + tid;
      int r = flat >> 4, c = flat & 15;
      Xs[r][c] = x[(size_t)(bm + r) * K_IN + k0 + c];
      float w = W[(size_t)(bn + r) * K_IN + k0 + c];
#pragma unroll
      for (int rr = 0; rr < RANK; ++rr)
        w += LSCALE * lB[(bn + r) * RANK + rr] * lA[rr * K_IN + k0 + c];
      Ws[r][c] = w;
    }
    __syncthreads();
#pragma unroll
    for (int kk = 0; kk < 16; ++kk) {
      float av[4], bv[4];
#pragma unroll
      for (int i = 0; i < 4; ++i) av[i] = Xs[ty * 4 + i][kk];
#pragma unroll
      for (int j = 0; j < 4; ++j) bv[j] = Ws[tx * 4 + j][kk];
#pragma unroll
      for (int i = 0; i < 4; ++i)
#pragma unroll
        for (int j = 0; j < 4; ++j) acc[i][j] += av[i] * bv[j];
    }
    __syncthreads();
  }
#pragma unroll
  for (int i = 0; i < 4; ++i)
#pragma unroll
    for (int j = 0; j < 4; ++j)
      out[(size_t)(bm + ty * 4 + i) * N_OUT + bn + tx * 4 + j] =
          acc[i][j] + bias[bn + tx * 4 + j];
}

extern "C" void kernel_launch(void* const* d_in, const int* in_sizes, int n_in,
                              void* d_out, int out_size, void* d_ws, size_t ws_size,
                              hipStream_t stream) {
  const float* x  = (const float*)d_in[0];
  const float* W  = (const float*)d_in[1];
  const float* b  = (const float*)d_in[2];
  const float* lA = (const float*)d_in[3];
  const float* lB = (const float*)d_in[4];
  float* out = (float*)d_out;

  const size_t weff_bytes = (size_t)N_OUT * K_IN * 2;    // 32 MB
  const size_t xb_bytes   = (size_t)M_ROWS * K_IN * 2;   // 128 MB

  if (ws_size >= weff_bytes + xb_bytes) {
    unsigned short* Weff = (unsigned short*)d_ws;
    unsigned short* Xb   = (unsigned short*)((char*)d_ws + weff_bytes);
    fold_w_kernel<<<(int)(((size_t)N_OUT * K_IN / 4) / 256), 256, 0, stream>>>(W, lA, lB, Weff);
    cvt_x_kernel<<<(int)(((size_t)M_ROWS * K_IN / 8) / 256), 256, 0, stream>>>(x, Xb);
    gemm_kernel<<<(M_ROWS / 256) * (N_OUT / 256), 512, 0, stream>>>(Xb, Weff, b, out);
  } else {
    dim3 grid(N_OUT / 64, M_ROWS / 64);
    fallback_kernel<<<grid, 256, 0, stream>>>(x, W, b, lA, lB, out);
  }
}

// Round 8
// 630.344 us; speedup vs baseline: 6.4739x; 6.4739x over previous
//
#include <hip/hip_runtime.h>
#include <cstdint>

#define K_IN   4096
#define N_OUT  4096
#define M_ROWS 16384
#define RANK   8
#define LSCALE 1.0f    // alpha/rank = 8/8
#define NT     64      // K_IN / 64  (BK=64 K-tiles)
#define ROWB   8192    // K_IN * 2 bytes per global row
#define AHALF  1048576 // 128 rows * ROWB

typedef __attribute__((ext_vector_type(8))) short  short8;
typedef __attribute__((ext_vector_type(4))) float  floatx4;

__device__ __forceinline__ unsigned short f2bf(float f) {
  uint32_t u = __float_as_uint(f);
  u += 0x7FFFu + ((u >> 16) & 1u);
  return (unsigned short)(u >> 16);
}

__global__ __launch_bounds__(256) void fold_w_kernel(
    const float* __restrict__ W, const float* __restrict__ lA,
    const float* __restrict__ lB, unsigned short* __restrict__ Weff) {
  int idx = blockIdx.x * 256 + threadIdx.x;
  int o = idx >> 10;
  int k = (idx & 1023) << 2;
  float4 w = *reinterpret_cast<const float4*>(W + (size_t)o * K_IN + k);
#pragma unroll
  for (int r = 0; r < RANK; ++r) {
    float s = LSCALE * lB[o * RANK + r];
    float4 a = *reinterpret_cast<const float4*>(lA + r * K_IN + k);
    w.x += s * a.x; w.y += s * a.y; w.z += s * a.z; w.w += s * a.w;
  }
  ushort4 p;
  p.x = f2bf(w.x); p.y = f2bf(w.y); p.z = f2bf(w.z); p.w = f2bf(w.w);
  *reinterpret_cast<ushort4*>(Weff + (size_t)o * K_IN + k) = p;
}

__global__ __launch_bounds__(256) void cvt_x_kernel(
    const float* __restrict__ x, unsigned short* __restrict__ xb) {
  size_t i = ((size_t)blockIdx.x * 256 + threadIdx.x) * 8;
  float4 a = *reinterpret_cast<const float4*>(x + i);
  float4 c = *reinterpret_cast<const float4*>(x + i + 4);
  uint4 v;
  v.x = (uint32_t)f2bf(a.x) | ((uint32_t)f2bf(a.y) << 16);
  v.y = (uint32_t)f2bf(a.z) | ((uint32_t)f2bf(a.w) << 16);
  v.z = (uint32_t)f2bf(c.x) | ((uint32_t)f2bf(c.y) << 16);
  v.w = (uint32_t)f2bf(c.z) | ((uint32_t)f2bf(c.w) << 16);
  *reinterpret_cast<uint4*>(xb + i) = v;
}

__device__ __forceinline__ void gload_lds16(const void* g, void* l) {
  __builtin_amdgcn_global_load_lds(
      (const __attribute__((address_space(1))) void*)g,
      (__attribute__((address_space(3))) void*)l, 16, 0, 0);
}

// ---------------------------------------------------------------------------
// m201-template port. 256x256 tile, BK=64, 512 threads (8 waves: 2M x 4N).
// LDS 128KB = 2 tile-buffers x 4 half-tiles [128 rows][64 bf16] (16KB each):
// halves 0,1 = A rows 0-127 / 128-255; halves 2,3 = B rows 0-127 / 128-255.
// st_16x32 swizzle: phys = logical ^ ((logical>>9 & 1)<<5) (involution).
// global_load_lds writes linearly -> SOURCE pre-swizzled (rule 21):
// thread tid covers linear bytes tid*16 and 8192+tid*16 of a half ->
// logical (row = tid>>3, colbyte = ((tid&7)<<4)^(tid&32)) and (+64 rows).
// Phases: one C-quadrant (mq,nq of the wave's 128x64) per phase, K=64:
//  P0: ds A(mq0)8 + B(nq0)4 | stage H[4t+7]  | BAR | MFMA(0,0) | BAR
//  P1: ds A(mq1)8           | stage H[4t+8]  | BAR | MFMA(1,0) | BAR
//  P2: ds B(nq1)4           | stage H[4t+9]  | BAR | MFMA(1,1) | BAR
//  P3: (no ds)              | stage H[4t+10] | vmcnt | BAR | MFMA(0,1) | BAR
// (A regs ping-pong afA/afB so A0 is NOT re-read at P3; B single set bfC.)
// Stage schedule: half-tile H[k] (tile k>>2, half k&3) staged at phase k-7
// (prologue stages H[0..6] = 7 half-tiles = the template's depth).
// vmcnt ledger (2 loads/half/thread, in-order): W at end-P3 of tile t must
// retire through H[4t+7] (tile t+1 complete; its first read is P0(t+1)).
// Issued <= H[4t+10] -> leftover = H[4t+8..10] = 3 halves = vmcnt(6). Never
// drains below 6 mid-loop. Tail: t=NT-2 -> vmcnt(0); t=NT-1 -> skip.
// WAR per half (stage into region vs last ds_read of previous tenant):
//  A0(t+2) staged P1(t), A0(t) last read P0(t)  -> 1 barrier apart  OK
//  A1(t+2) staged P2(t), A1(t) last read P1(t)  -> OK
//  B0(t+2) staged P3(t), B0(t) last read P0(t)  -> OK
//  B1(t+1) staged P0(t) into the OTHER buffer   -> OK
// R7 lesson: NO aggressive launch_bounds min-waves (forced VGPR=64 ->
// accumulator spill, 19.5 GB scratch traffic). (512,2) caps at 256.
// ---------------------------------------------------------------------------
__global__ __launch_bounds__(512, 2) void gemm_kernel(
    const unsigned short* __restrict__ Xb, const unsigned short* __restrict__ Wb,
    const float* __restrict__ bias, float* __restrict__ out) {
  __shared__ alignas(16) char lds[2 * 65536];   // 128 KiB

  const int tid  = threadIdx.x;
  const int wave = tid >> 6, lane = tid & 63;
  const int wr = wave >> 2, wc = wave & 3;      // 2 (M) x 4 (N) wave grid
  const int l15 = lane & 15, sq = lane >> 4;

  // XCD swizzle: 1024 blocks (%8==0), contiguous 128-tile chunk per XCD
  int bx  = blockIdx.x;
  int sbx = (bx & 7) * 128 + (bx >> 3);
  const int mt = sbx >> 4;   // 0..63
  const int nt = sbx & 15;   // 0..15

  // staging source decode (pre-swizzle, verified involution):
  const int rstg = tid >> 3;                          // 0..63
  const int cbst = ((tid & 7) << 4) ^ (tid & 32);     // 0..127, 16B-aligned
  const char* aBase = (const char*)Xb + (size_t)(mt * 256 + rstg) * ROWB + cbst;
  const char* bBase = (const char*)Wb + (size_t)(nt * 256 + rstg) * ROWB + cbst;

#define STAGE(H) do {                                                     \
    int th_ = (H) >> 2, hh_ = (H) & 3;                                    \
    const char* src_ = ((hh_ < 2) ? aBase + (size_t)hh_ * AHALF           \
                                  : bBase + (size_t)(hh_ - 2) * AHALF)    \
                       + th_ * 128;                                       \
    char* dst_ = lds + (th_ & 1) * 65536 + hh_ * 16384 + tid * 16;        \
    gload_lds16(src_, dst_);                                              \
    gload_lds16(src_ + (size_t)64 * ROWB, dst_ + 8192);                   \
  } while (0)
#define BAR() do { asm volatile("" ::: "memory");                         \
    __builtin_amdgcn_s_barrier();                                         \
    asm volatile("" ::: "memory"); } while (0)
#define LDSWZ(ROW, COLB) ((((ROW) << 7) | (COLB)) ^ (((ROW) & 4) << 3))
#define LOAD_A(DST, MQ) do {                                              \
    const char* Ab_ = lds + tb + wr * 16384;                              \
    _Pragma("unroll")                                                     \
    for (int ks = 0; ks < 2; ++ks)                                        \
      _Pragma("unroll")                                                   \
      for (int fi = 0; fi < 4; ++fi) {                                    \
        int row_ = (MQ) * 64 + fi * 16 + l15;                             \
        int cb_  = ks * 64 + sq * 16;                                     \
        DST[ks * 4 + fi] =                                                \
            *reinterpret_cast<const short8*>(Ab_ + LDSWZ(row_, cb_));     \
      } } while (0)
#define LOAD_B(DST, NQ) do {                                              \
    const char* Bb_ = lds + tb + (2 + (wc >> 1)) * 16384;                 \
    _Pragma("unroll")                                                     \
    for (int ks = 0; ks < 2; ++ks)                                        \
      _Pragma("unroll")                                                   \
      for (int fj = 0; fj < 2; ++fj) {                                    \
        int row_ = (wc & 1) * 64 + (NQ) * 32 + fj * 16 + l15;             \
        int cb_  = ks * 64 + sq * 16;                                     \
        DST[ks * 2 + fj] =                                                \
            *reinterpret_cast<const short8*>(Bb_ + LDSWZ(row_, cb_));     \
      } } while (0)
#define MFMA_Q(MQ, NQ, AF, BF) do {                                       \
    __builtin_amdgcn_s_setprio(1);                                        \
    _Pragma("unroll")                                                     \
    for (int ks = 0; ks < 2; ++ks)                                        \
      _Pragma("unroll")                                                   \
      for (int fi = 0; fi < 4; ++fi)                                      \
        _Pragma("unroll")                                                 \
        for (int fj = 0; fj < 2; ++fj)                                    \
          acc[(MQ) * 4 + fi][(NQ) * 2 + fj] =                             \
              __builtin_amdgcn_mfma_f32_16x16x32_bf16(                    \
                  AF[ks * 4 + fi], BF[ks * 2 + fj],                       \
                  acc[(MQ) * 4 + fi][(NQ) * 2 + fj], 0, 0, 0);            \
    __builtin_amdgcn_s_setprio(0); } while (0)

  floatx4 acc[8][4];
#pragma unroll
  for (int i = 0; i < 8; ++i)
#pragma unroll
    for (int j = 0; j < 4; ++j)
      acc[i][j] = (floatx4){0.f, 0.f, 0.f, 0.f};

  // prologue: 7 half-tiles (tile0 complete + tile1's A0,A1,B0);
  // vmcnt(6) retires tile0's 8 loads, leaves 6 in flight.
  for (int h = 0; h < 7; ++h) STAGE(h);
  asm volatile("s_waitcnt vmcnt(6)" ::: "memory");
  BAR();

  short8 afA[8], afB[8], bfC[4];

  for (int t = 0; t < NT; ++t) {
    const int tb = (t & 1) * 65536;
    const int p0 = 4 * t;

    // ---- P0: quadrant (0,0)
    LOAD_A(afA, 0);
    LOAD_B(bfC, 0);
    if (p0 + 7 < 4 * NT) STAGE(p0 + 7);
    BAR();
    MFMA_Q(0, 0, afA, bfC);
    BAR();

    // ---- P1: quadrant (1,0)
    LOAD_A(afB, 1);
    if (p0 + 8 < 4 * NT) STAGE(p0 + 8);
    BAR();
    MFMA_Q(1, 0, afB, bfC);
    BAR();

    // ---- P2: quadrant (1,1)
    LOAD_B(bfC, 1);
    if (p0 + 9 < 4 * NT) STAGE(p0 + 9);
    BAR();
    MFMA_Q(1, 1, afB, bfC);
    BAR();

    // ---- P3: quadrant (0,1); the single per-tile vmcnt cert
    if (p0 + 10 < 4 * NT) STAGE(p0 + 10);
    if (t <= NT - 3)      asm volatile("s_waitcnt vmcnt(6)" ::: "memory");
    else if (t == NT - 2) asm volatile("s_waitcnt vmcnt(0)" ::: "memory");
    BAR();
    MFMA_Q(0, 1, afA, bfC);
    BAR();
  }
#undef STAGE
#undef LOAD_A
#undef LOAD_B
#undef MFMA_Q

  // epilogue: C/D layout col=lane&15, row=(lane>>4)*4+reg (m89/m91 verified)
  const int row0 = mt * 256 + wr * 128 + sq * 4;
  const int col0 = nt * 256 + wc * 64 + l15;
#pragma unroll
  for (int j = 0; j < 4; ++j) {
    int col = col0 + j * 16;
    float bv = bias[col];
#pragma unroll
    for (int i = 0; i < 8; ++i) {
      int rowb = row0 + i * 16;
#pragma unroll
      for (int rr = 0; rr < 4; ++rr)
        out[(size_t)(rowb + rr) * N_OUT + col] = acc[i][j][rr] + bv;
    }
  }
}

// self-contained correct fallback (only if ws too small): tiled fp32
__global__ __launch_bounds__(256) void fallback_kernel(
    const float* __restrict__ x, const float* __restrict__ W,
    const float* __restrict__ bias, const float* __restrict__ lA,
    const float* __restrict__ lB, float* __restrict__ out) {
  __shared__ float Xs[64][17];
  __shared__ float Ws[64][17];
  int tid = threadIdx.x;
  int tx = tid & 15, ty = tid >> 4;
  int bm = blockIdx.y * 64, bn = blockIdx.x * 64;
  float acc[4][4] = {};
  for (int k0 = 0; k0 < K_IN; k0 += 16) {
#pragma unroll
    for (int q = 0; q < 4; ++q) {
      int flat = q * 256 + tid;
      int r = flat >> 4, c = flat & 15;
      Xs[r][c] = x[(size_t)(bm + r) * K_IN + k0 + c];
      float w = W[(size_t)(bn + r) * K_IN + k0 + c];
#pragma unroll
      for (int rr = 0; rr < RANK; ++rr)
        w += LSCALE * lB[(bn + r) * RANK + rr] * lA[rr * K_IN + k0 + c];
      Ws[r][c] = w;
    }
    __syncthreads();
#pragma unroll
    for (int kk = 0; kk < 16; ++kk) {
      float av[4], bv[4];
#pragma unroll
      for (int i = 0; i < 4; ++i) av[i] = Xs[ty * 4 + i][kk];
#pragma unroll
      for (int j = 0; j < 4; ++j) bv[j] = Ws[tx * 4 + j][kk];
#pragma unroll
      for (int i = 0; i < 4; ++i)
#pragma unroll
        for (int j = 0; j < 4; ++j) acc[i][j] += av[i] * bv[j];
    }
    __syncthreads();
  }
#pragma unroll
  for (int i = 0; i < 4; ++i)
#pragma unroll
    for (int j = 0; j < 4; ++j)
      out[(size_t)(bm + ty * 4 + i) * N_OUT + bn + tx * 4 + j] =
          acc[i][j] + bias[bn + tx * 4 + j];
}

extern "C" void kernel_launch(void* const* d_in, const int* in_sizes, int n_in,
                              void* d_out, int out_size, void* d_ws, size_t ws_size,
                              hipStream_t stream) {
  const float* x  = (const float*)d_in[0];
  const float* W  = (const float*)d_in[1];
  const float* b  = (const float*)d_in[2];
  const float* lA = (const float*)d_in[3];
  const float* lB = (const float*)d_in[4];
  float* out = (float*)d_out;

  const size_t weff_bytes = (size_t)N_OUT * K_IN * 2;    // 32 MB
  const size_t xb_bytes   = (size_t)M_ROWS * K_IN * 2;   // 128 MB

  if (ws_size >= weff_bytes + xb_bytes) {
    unsigned short* Weff = (unsigned short*)d_ws;
    unsigned short* Xb   = (unsigned short*)((char*)d_ws + weff_bytes);
    fold_w_kernel<<<(int)(((size_t)N_OUT * K_IN / 4) / 256), 256, 0, stream>>>(W, lA, lB, Weff);
    cvt_x_kernel<<<(int)(((size_t)M_ROWS * K_IN / 8) / 256), 256, 0, stream>>>(x, Xb);
    gemm_kernel<<<(M_ROWS / 256) * (N_OUT / 256), 512, 0, stream>>>(Xb, Weff, b, out);
  } else {
    dim3 grid(N_OUT / 64, M_ROWS / 64);
    fallback_kernel<<<grid, 256, 0, stream>>>(x, W, b, lA, lB, out);
  }
}